// Round 2
// baseline (1068.736 us; speedup 1.0000x reference)
//
#include <hip/hip_runtime.h>
#include <hip/hip_bf16.h>
#include <math.h>

#define D_MODEL 1024
#define NHEAD 16
#define HDIM 64
#define BATCH 2
#define SEQ 2048
#define KDIM 1024
#define SCALE 0.125f

// ---------- GEMM: out = A[M][1024] @ W[Nout][1024]^T + bias ----------
// MODE 0: plain row-major write to out[M][Nout]
// MODE 1: scatter to qkv workspace [3][B*H][SEQ][HDIM]
template<int MODE>
__global__ __launch_bounds__(256) void gemm64(const float* __restrict__ A,
                                              const float* __restrict__ W,
                                              const float* __restrict__ bias,
                                              float* __restrict__ out,
                                              int Nout)
{
    __shared__ float As[16][68];   // [k][m] k-major
    __shared__ float Bs[16][68];   // [k][n] k-major
    const int t  = threadIdx.x;
    const int tx = t & 15, ty = t >> 4;
    const int lrow = t >> 2, lqd = t & 3;
    const int m0 = blockIdx.y * 64;
    const int n0 = blockIdx.x * 64;

    float acc[4][4] = {};

    for (int k0 = 0; k0 < KDIM; k0 += 16) {
        __syncthreads();
        float4 av = *(const float4*)&A[(size_t)(m0 + lrow) * KDIM + k0 + lqd * 4];
        float4 bv = *(const float4*)&W[(size_t)(n0 + lrow) * KDIM + k0 + lqd * 4];
        As[lqd*4+0][lrow] = av.x;
        As[lqd*4+1][lrow] = av.y;
        As[lqd*4+2][lrow] = av.z;
        As[lqd*4+3][lrow] = av.w;
        Bs[lqd*4+0][lrow] = bv.x;
        Bs[lqd*4+1][lrow] = bv.y;
        Bs[lqd*4+2][lrow] = bv.z;
        Bs[lqd*4+3][lrow] = bv.w;
        __syncthreads();
        #pragma unroll
        for (int kk = 0; kk < 16; ++kk) {
            float4 a4 = *(const float4*)&As[kk][ty*4];
            float4 b4 = *(const float4*)&Bs[kk][tx*4];
            float a[4] = {a4.x, a4.y, a4.z, a4.w};
            float b[4] = {b4.x, b4.y, b4.z, b4.w};
            #pragma unroll
            for (int i2 = 0; i2 < 4; ++i2)
                #pragma unroll
                for (int j2 = 0; j2 < 4; ++j2)
                    acc[i2][j2] = fmaf(a[i2], b[j2], acc[i2][j2]);
        }
    }

    float4 bb = *(const float4*)&bias[n0 + tx*4];
    float bias4[4] = {bb.x, bb.y, bb.z, bb.w};

    #pragma unroll
    for (int ii = 0; ii < 4; ++ii) {
        const int m = m0 + ty*4 + ii;
        float4 r;
        r.x = acc[ii][0] + bias4[0];
        r.y = acc[ii][1] + bias4[1];
        r.z = acc[ii][2] + bias4[2];
        r.w = acc[ii][3] + bias4[3];
        if (MODE == 0) {
            *(float4*)&out[(size_t)m * Nout + n0 + tx*4] = r;
        } else {
            const int which = n0 >> 10;         // 0=q 1=k 2=v
            const int h     = (n0 >> 6) & 15;   // head
            const int b     = m >> 11;
            const int nq    = m & 2047;
            *(float4*)&out[(((size_t)which*BATCH*NHEAD + b*NHEAD + h)*SEQ + nq)*HDIM + tx*4] = r;
        }
    }
}

// ---------- Flash attention (fp32), one block per (q-tile of 64, b*h) ----------
__global__ __launch_bounds__(256) void attn_kernel(const float* __restrict__ qkv,
                                                   float* __restrict__ out)
{
    __shared__ float Qs[64][68];   // [d][i]  (pre-scaled by SCALE)
    __shared__ float Ks[64][68];   // [d][j]
    __shared__ float Vs[64][68];   // [j][d]
    __shared__ float Ps[64][68];   // [i][j]

    const int t  = threadIdx.x;
    const int tx = t & 15, ty = t >> 4;
    const int lrow = t >> 2, lqd = t & 3;
    const int q0 = blockIdx.x * 64;
    const int bh = blockIdx.y;     // 0..31

    const float* Qg = qkv + ((size_t)(0*BATCH*NHEAD + bh)) * SEQ * HDIM;
    const float* Kg = qkv + ((size_t)(1*BATCH*NHEAD + bh)) * SEQ * HDIM;
    const float* Vg = qkv + ((size_t)(2*BATCH*NHEAD + bh)) * SEQ * HDIM;

    // load Q tile transposed, pre-scaled
    #pragma unroll
    for (int j = 0; j < 4; ++j) {
        const int d0 = lqd*4 + j*16;
        float4 qv = *(const float4*)&Qg[(size_t)(q0 + lrow)*HDIM + d0];
        Qs[d0+0][lrow] = qv.x * SCALE;
        Qs[d0+1][lrow] = qv.y * SCALE;
        Qs[d0+2][lrow] = qv.z * SCALE;
        Qs[d0+3][lrow] = qv.w * SCALE;
    }

    float o[4][4] = {};
    float mOld[4], lsum[4];
    #pragma unroll
    for (int ii = 0; ii < 4; ++ii) { mOld[ii] = -1e30f; lsum[ii] = 0.f; }

    for (int kt = 0; kt < SEQ; kt += 64) {
        __syncthreads();   // previous PV done before overwriting K/V
        #pragma unroll
        for (int j = 0; j < 4; ++j) {
            const int d0 = lqd*4 + j*16;
            float4 kv = *(const float4*)&Kg[(size_t)(kt + lrow)*HDIM + d0];
            Ks[d0+0][lrow] = kv.x;
            Ks[d0+1][lrow] = kv.y;
            Ks[d0+2][lrow] = kv.z;
            Ks[d0+3][lrow] = kv.w;
            float4 vv = *(const float4*)&Vg[(size_t)(kt + lrow)*HDIM + d0];
            *(float4*)&Vs[lrow][d0] = vv;
        }
        __syncthreads();

        // S = (Q*scale) . K^T   (64x64 tile, 4x4 per thread)
        float s[4][4] = {};
        #pragma unroll 8
        for (int d = 0; d < 64; ++d) {
            float4 qa = *(const float4*)&Qs[d][ty*4];
            float4 kb = *(const float4*)&Ks[d][tx*4];
            float a[4] = {qa.x, qa.y, qa.z, qa.w};
            float b[4] = {kb.x, kb.y, kb.z, kb.w};
            #pragma unroll
            for (int i2 = 0; i2 < 4; ++i2)
                #pragma unroll
                for (int j2 = 0; j2 < 4; ++j2)
                    s[i2][j2] = fmaf(a[i2], b[j2], s[i2][j2]);
        }

        // online softmax per row (row group = 16 lanes sharing ty)
        #pragma unroll
        for (int ii = 0; ii < 4; ++ii) {
            float rmax = fmaxf(fmaxf(s[ii][0], s[ii][1]), fmaxf(s[ii][2], s[ii][3]));
            #pragma unroll
            for (int off = 8; off >= 1; off >>= 1)
                rmax = fmaxf(rmax, __shfl_xor(rmax, off, 16));
            const float mNew = fmaxf(mOld[ii], rmax);
            const float alpha = expf(mOld[ii] - mNew);
            float p0 = expf(s[ii][0] - mNew);
            float p1 = expf(s[ii][1] - mNew);
            float p2 = expf(s[ii][2] - mNew);
            float p3 = expf(s[ii][3] - mNew);
            float rsum = p0 + p1 + p2 + p3;
            #pragma unroll
            for (int off = 8; off >= 1; off >>= 1)
                rsum += __shfl_xor(rsum, off, 16);
            lsum[ii] = lsum[ii]*alpha + rsum;
            mOld[ii] = mNew;
            o[ii][0] *= alpha; o[ii][1] *= alpha; o[ii][2] *= alpha; o[ii][3] *= alpha;
            float4 pr; pr.x = p0; pr.y = p1; pr.z = p2; pr.w = p3;
            *(float4*)&Ps[ty*4+ii][tx*4] = pr;
        }
        __syncthreads();

        // O += P . V
        #pragma unroll 8
        for (int j = 0; j < 64; ++j) {
            float4 vv = *(const float4*)&Vs[j][tx*4];
            #pragma unroll
            for (int ii = 0; ii < 4; ++ii) {
                const float p = Ps[ty*4+ii][j];
                o[ii][0] = fmaf(p, vv.x, o[ii][0]);
                o[ii][1] = fmaf(p, vv.y, o[ii][1]);
                o[ii][2] = fmaf(p, vv.z, o[ii][2]);
                o[ii][3] = fmaf(p, vv.w, o[ii][3]);
            }
        }
    }

    // write out [B][SEQ][D_MODEL] with head offset
    const int b = bh >> 4, h = bh & 15;
    #pragma unroll
    for (int ii = 0; ii < 4; ++ii) {
        const float inv = 1.0f / lsum[ii];
        float4 r;
        r.x = o[ii][0]*inv; r.y = o[ii][1]*inv; r.z = o[ii][2]*inv; r.w = o[ii][3]*inv;
        *(float4*)&out[((size_t)(b*SEQ + q0 + ty*4 + ii))*D_MODEL + h*HDIM + tx*4] = r;
    }
}

extern "C" void kernel_launch(void* const* d_in, const int* in_sizes, int n_in,
                              void* d_out, int out_size, void* d_ws, size_t ws_size,
                              hipStream_t stream)
{
    const float* x      = (const float*)d_in[0];
    const float* qkv_w  = (const float*)d_in[1];
    const float* qkv_b  = (const float*)d_in[2];
    const float* proj_w = (const float*)d_in[3];
    const float* proj_b = (const float*)d_in[4];
    float* out  = (float*)d_out;
    float* qkv  = (float*)d_ws;                                   // [3][B*H][SEQ][HDIM] fp32 (25.2 MB)
    float* attn = qkv + (size_t)3*BATCH*NHEAD*SEQ*HDIM;           // [4096][1024] fp32 (16.8 MB)

    dim3 blk(256);
    // 1) QKV projection: [4096,1024] @ [3072,1024]^T, scatter to q/k/v layout
    gemm64<1><<<dim3(3*D_MODEL/64, BATCH*SEQ/64), blk, 0, stream>>>(x, qkv_w, qkv_b, qkv, 3*D_MODEL);
    // 2) flash attention per (q-tile, b*h)
    attn_kernel<<<dim3(SEQ/64, BATCH*NHEAD), blk, 0, stream>>>(qkv, attn);
    // 3) output projection: [4096,1024] @ [1024,1024]^T -> d_out
    gemm64<0><<<dim3(D_MODEL/64, BATCH*SEQ/64), blk, 0, stream>>>(attn, proj_w, proj_b, out, D_MODEL);
}

// Round 7
// 259.218 us; speedup vs baseline: 4.1229x; 4.1229x over previous
//
#include <hip/hip_runtime.h>
#include <hip/hip_bf16.h>
#include <math.h>

#define D_MODEL 1024
#define NHEAD 16
#define HDIM 64
#define BATCH 2
#define SEQ 2048
#define SCALE 0.125f

typedef unsigned short u16;
typedef __attribute__((ext_vector_type(8))) short bf16x8;
typedef __attribute__((ext_vector_type(4))) float f32x4;

__device__ __forceinline__ f32x4 mfma_bf16(bf16x8 a, bf16x8 b, f32x4 c) {
    return __builtin_amdgcn_mfma_f32_16x16x32_bf16(a, b, c, 0, 0, 0);
}
__device__ __forceinline__ void gload_lds16(const void* g, void* l) {
    __builtin_amdgcn_global_load_lds(
        (const __attribute__((address_space(1))) unsigned int*)g,
        (__attribute__((address_space(3))) unsigned int*)l, 16, 0, 0);
}
__device__ __forceinline__ u16 f2bf(float f) {
    unsigned u = __builtin_bit_cast(unsigned, f);
    return (u16)((u + 0x7FFFu + ((u >> 16) & 1u)) >> 16);
}

// ---------------- f32 -> bf16 conversion (memory-bound) ----------------
__global__ __launch_bounds__(256) void cvt_bf16(const float* __restrict__ in,
                                                u16* __restrict__ out, int n) {
    int i = (blockIdx.x * 256 + threadIdx.x) * 8;
    if (i >= n) return;
    float4 a = *(const float4*)&in[i];
    float4 b = *(const float4*)&in[i + 4];
    ushort4 o0 = { f2bf(a.x), f2bf(a.y), f2bf(a.z), f2bf(a.w) };
    ushort4 o1 = { f2bf(b.x), f2bf(b.y), f2bf(b.z), f2bf(b.w) };
    *(ushort4*)&out[i] = o0;
    *(ushort4*)&out[i + 4] = o1;
}

// ---------------- MFMA GEMM: C[m][n] = sum_k A[m][k]*W[n][k] + bias ----------------
// 128x128 tile, BK=64, 4 waves each 64x64 (4x4 frags of 16x16x32).
// LDS tiles [128 rows][64 k] bf16 (128B rows), XOR swizzle byte^=((row&7)<<4):
// global_load_lds writes linearly; SOURCE address is inverse-swizzled (rule #21).
// MODE 0: fp32 out [M][1024] (+proj bias)
// MODE 1: bf16 scatter: n in [0,1024)=q, [1024,2048)=k -> [bh][seq][64];
//         [2048,3072)=v -> TRANSPOSED [bh][d][seq]
template<int MODE>
__global__ __launch_bounds__(256) void gemm_mfma(const u16* __restrict__ A,
                                                 const u16* __restrict__ W,
                                                 const float* __restrict__ bias,
                                                 float* __restrict__ outf,
                                                 u16* __restrict__ qw,
                                                 u16* __restrict__ kw,
                                                 u16* __restrict__ vtw)
{
    __shared__ u16 As[2][8192];
    __shared__ u16 Bs[2][8192];
    const int t = threadIdx.x, lane = t & 63, w = t >> 6;
    const int wr = w >> 1, wc = w & 1;
    const int lr = lane & 15, lk = lane >> 4;
    const int m0 = blockIdx.y * 128, n0 = blockIdx.x * 128;

    // staging constants: physical LDS byte p -> (row, inverse-swizzled k-offset)
    int srow[4], soff[4];
    #pragma unroll
    for (int i = 0; i < 4; ++i) {
        int p = (w * 4 + i) * 1024 + lane * 16;
        int row = p >> 7;
        srow[i] = row;
        soff[i] = ((p ^ ((row & 7) << 4)) & 127) >> 1;  // element offset in k
    }

    f32x4 acc[4][4];
    #pragma unroll
    for (int i = 0; i < 4; ++i)
        #pragma unroll
        for (int j = 0; j < 4; ++j)
            #pragma unroll
            for (int r = 0; r < 4; ++r) acc[i][j][r] = 0.f;

    auto stage = [&](int buf, int k0) {
        #pragma unroll
        for (int i = 0; i < 4; ++i) {
            gload_lds16(&A[(size_t)(m0 + srow[i]) * 1024 + k0 + soff[i]],
                        &As[buf][(w * 4 + i) * 512]);
            gload_lds16(&W[(size_t)(n0 + srow[i]) * 1024 + k0 + soff[i]],
                        &Bs[buf][(w * 4 + i) * 512]);
        }
    };

    stage(0, 0);
    __syncthreads();

    for (int kt = 0; kt < 16; ++kt) {
        int buf = kt & 1;
        if (kt < 15) stage(buf ^ 1, (kt + 1) * 64);
        #pragma unroll
        for (int kk = 0; kk < 2; ++kk) {
            const int kb2 = (kk * 32 + lk * 8) * 2;   // k byte offset within row
            bf16x8 am[4], bn[4];
            #pragma unroll
            for (int mf = 0; mf < 4; ++mf) {
                int row = wr * 64 + mf * 16 + lr;
                am[mf] = *(const bf16x8*)((const char*)As[buf] + row * 128 + (kb2 ^ ((row & 7) << 4)));
            }
            #pragma unroll
            for (int nf = 0; nf < 4; ++nf) {
                int row = wc * 64 + nf * 16 + lr;
                bn[nf] = *(const bf16x8*)((const char*)Bs[buf] + row * 128 + (kb2 ^ ((row & 7) << 4)));
            }
            #pragma unroll
            for (int mf = 0; mf < 4; ++mf)
                #pragma unroll
                for (int nf = 0; nf < 4; ++nf)
                    acc[mf][nf] = mfma_bf16(am[mf], bn[nf], acc[mf][nf]);
        }
        __syncthreads();
    }

    // epilogue: C/D layout col = lane&15, row = (lane>>4)*4 + reg
    if (MODE == 0) {
        #pragma unroll
        for (int nf = 0; nf < 4; ++nf) {
            int n = n0 + wc * 64 + nf * 16 + lr;
            float bv = bias[n];
            #pragma unroll
            for (int mf = 0; mf < 4; ++mf) {
                int m = m0 + wr * 64 + mf * 16 + lk * 4;
                #pragma unroll
                for (int r = 0; r < 4; ++r)
                    outf[(size_t)(m + r) * 1024 + n] = acc[mf][nf][r] + bv;
            }
        }
    } else {
        #pragma unroll
        for (int nf = 0; nf < 4; ++nf) {
            int n = n0 + wc * 64 + nf * 16 + lr;
            int which = n >> 10, h = (n >> 6) & 15, d = n & 63;
            float bv = bias[n];
            #pragma unroll
            for (int mf = 0; mf < 4; ++mf) {
                int m = m0 + wr * 64 + mf * 16 + lk * 4;
                int b = m >> 11, sq = m & 2047;
                int bh = b * NHEAD + h;
                if (which == 2) {
                    ushort4 v4;
                    v4.x = f2bf(acc[mf][nf][0] + bv);
                    v4.y = f2bf(acc[mf][nf][1] + bv);
                    v4.z = f2bf(acc[mf][nf][2] + bv);
                    v4.w = f2bf(acc[mf][nf][3] + bv);
                    *(ushort4*)&vtw[((size_t)bh * 64 + d) * SEQ + sq] = v4;
                } else {
                    u16* dst = (which ? kw : qw) + ((size_t)bh * SEQ + sq) * 64 + d;
                    dst[0]   = f2bf(acc[mf][nf][0] + bv);
                    dst[64]  = f2bf(acc[mf][nf][1] + bv);
                    dst[128] = f2bf(acc[mf][nf][2] + bv);
                    dst[192] = f2bf(acc[mf][nf][3] + bv);
                }
            }
        }
    }
}

// ---------------- Flash attention, bf16 MFMA ----------------
// block = 256 thr (4 waves), QBLK=64 (16 q-rows/wave), KVBLK=64.
// Q in registers; K [kv][64] and Vt [d][kv=64] double-buffered in LDS (swizzled,
// staged via global_load_lds); P through swizzled LDS (wave-local strip).
__global__ __launch_bounds__(256) void attn_mfma(const u16* __restrict__ qg,
                                                 const u16* __restrict__ kg,
                                                 const u16* __restrict__ vtg,
                                                 u16* __restrict__ og)
{
    __shared__ u16 Ks[2][4096];
    __shared__ u16 Vs[2][4096];
    __shared__ u16 Ps[4096];
    const int t = threadIdx.x, lane = t & 63, w = t >> 6;
    const int lr = lane & 15, lk = lane >> 4;
    const int q0 = blockIdx.x * 64;
    const int bh = blockIdx.y;
    const u16* Qbh = qg + (size_t)bh * SEQ * 64;
    const char* Kbytes = (const char*)(kg + (size_t)bh * SEQ * 64);
    const char* Vbytes = (const char*)(vtg + (size_t)bh * 64 * SEQ);

    // Q A-frags direct to regs: row = q0 + w*16 + lr, k = kk*32 + lk*8 ..+8
    bf16x8 qa[2];
    {
        const u16* qp = &Qbh[(size_t)(q0 + w * 16 + lr) * 64 + lk * 8];
        qa[0] = *(const bf16x8*)qp;
        qa[1] = *(const bf16x8*)(qp + 32);
    }

    int srow[2], soff[2];
    #pragma unroll
    for (int i = 0; i < 2; ++i) {
        int p = (w * 2 + i) * 1024 + lane * 16;
        int row = p >> 7;
        srow[i] = row;
        soff[i] = p ^ ((row & 7) << 4);   // inverse-swizzled byte offset (contains row*128)
    }

    auto stage = [&](int buf, int tt) {
        #pragma unroll
        for (int i = 0; i < 2; ++i) {
            // K tile is 8KB contiguous in global
            gload_lds16(Kbytes + (size_t)tt * 8192 + soff[i], &Ks[buf][(w * 2 + i) * 512]);
            // Vt rows stride SEQ*2=4096B, tile kv-offset tt*128B
            gload_lds16(Vbytes + (size_t)srow[i] * (SEQ * 2) + tt * 128 + (soff[i] & 127),
                        &Vs[buf][(w * 2 + i) * 512]);
        }
    };

    f32x4 o[4];
    float mrow[4], lsum[4];
    #pragma unroll
    for (int fd = 0; fd < 4; ++fd)
        #pragma unroll
        for (int r = 0; r < 4; ++r) o[fd][r] = 0.f;
    #pragma unroll
    for (int r = 0; r < 4; ++r) { mrow[r] = -1e30f; lsum[r] = 0.f; }

    stage(0, 0);
    __syncthreads();

    for (int kt = 0; kt < SEQ / 64; ++kt) {
        int buf = kt & 1;
        if (kt < SEQ / 64 - 1) stage(buf ^ 1, kt + 1);

        // S = Q.K^T : 4 kv-frags x 2 k-steps
        f32x4 s[4];
        #pragma unroll
        for (int nf = 0; nf < 4; ++nf)
            #pragma unroll
            for (int r = 0; r < 4; ++r) s[nf][r] = 0.f;
        #pragma unroll
        for (int kk = 0; kk < 2; ++kk) {
            const int kb2 = (kk * 32 + lk * 8) * 2;
            #pragma unroll
            for (int nf = 0; nf < 4; ++nf) {
                int row = nf * 16 + lr;   // kv row
                bf16x8 kb = *(const bf16x8*)((const char*)Ks[buf] + row * 128 + (kb2 ^ ((row & 7) << 4)));
                s[nf] = mfma_bf16(qa[kk], kb, s[nf]);
            }
        }

        // online softmax; lane's rows: q_local = lk*4 + r; cols nf*16 + lr
        float alpha[4];
        #pragma unroll
        for (int r = 0; r < 4; ++r) {
            float v0 = s[0][r] * SCALE, v1 = s[1][r] * SCALE,
                  v2 = s[2][r] * SCALE, v3 = s[3][r] * SCALE;
            float mx = fmaxf(fmaxf(v0, v1), fmaxf(v2, v3));
            #pragma unroll
            for (int o_ = 8; o_ >= 1; o_ >>= 1) mx = fmaxf(mx, __shfl_xor(mx, o_, 16));
            float mN = fmaxf(mrow[r], mx);
            float al = __expf(mrow[r] - mN);
            float p0 = __expf(v0 - mN), p1 = __expf(v1 - mN),
                  p2 = __expf(v2 - mN), p3 = __expf(v3 - mN);
            float rs = p0 + p1 + p2 + p3;
            #pragma unroll
            for (int o_ = 8; o_ >= 1; o_ >>= 1) rs += __shfl_xor(rs, o_, 16);
            lsum[r] = lsum[r] * al + rs;
            mrow[r] = mN;
            alpha[r] = al;
            const int qrow = w * 16 + lk * 4 + r;
            const int sw = (qrow & 7) << 4;
            char* pb = (char*)Ps + qrow * 128;
            *(u16*)(pb + (((0 * 16 + lr) * 2) ^ sw)) = f2bf(p0);
            *(u16*)(pb + (((1 * 16 + lr) * 2) ^ sw)) = f2bf(p1);
            *(u16*)(pb + (((2 * 16 + lr) * 2) ^ sw)) = f2bf(p2);
            *(u16*)(pb + (((3 * 16 + lr) * 2) ^ sw)) = f2bf(p3);
        }
        #pragma unroll
        for (int fd = 0; fd < 4; ++fd)
            #pragma unroll
            for (int r = 0; r < 4; ++r) o[fd][r] *= alpha[r];

        // O += P.V : P A-frags (wave-own strip, lgkmcnt-ordered), Vt B-frags
        bf16x8 pa[2];
        {
            const int qrow = w * 16 + lr;
            const int sw = (qrow & 7) << 4;
            #pragma unroll
            for (int kk = 0; kk < 2; ++kk)
                pa[kk] = *(const bf16x8*)((const char*)Ps + qrow * 128 + (((kk * 32 + lk * 8) * 2) ^ sw));
        }
        #pragma unroll
        for (int kk = 0; kk < 2; ++kk) {
            const int kb2 = (kk * 32 + lk * 8) * 2;
            #pragma unroll
            for (int fd = 0; fd < 4; ++fd) {
                int row = fd * 16 + lr;   // d row in Vt tile
                bf16x8 vb = *(const bf16x8*)((const char*)Vs[buf] + row * 128 + (kb2 ^ ((row & 7) << 4)));
                o[fd] = mfma_bf16(pa[kk], vb, o[fd]);
            }
        }
        __syncthreads();
    }

    // epilogue: out attn bf16 [4096][1024]; row = b*SEQ + q, col = h*64 + d
    const int b = bh >> 4, h = bh & 15;
    #pragma unroll
    for (int r = 0; r < 4; ++r) {
        float inv = 1.0f / lsum[r];
        size_t orow = (size_t)(b * SEQ + q0 + w * 16 + lk * 4 + r) * D_MODEL;
        #pragma unroll
        for (int fd = 0; fd < 4; ++fd)
            og[orow + h * 64 + fd * 16 + lr] = f2bf(o[fd][r] * inv);
    }
}

extern "C" void kernel_launch(void* const* d_in, const int* in_sizes, int n_in,
                              void* d_out, int out_size, void* d_ws, size_t ws_size,
                              hipStream_t stream)
{
    const float* x      = (const float*)d_in[0];
    const float* qkv_w  = (const float*)d_in[1];
    const float* qkv_b  = (const float*)d_in[2];
    const float* proj_w = (const float*)d_in[3];
    const float* proj_b = (const float*)d_in[4];
    float* out = (float*)d_out;

    u16* xbf     = (u16*)d_ws;                       // 4M elems; later reused as attn_out bf16
    u16* qkvwbf  = xbf + (size_t)4 * 1024 * 1024;    // 3M
    u16* projwbf = qkvwbf + (size_t)3 * 1024 * 1024; // 1M
    u16* qb      = projwbf + (size_t)1024 * 1024;    // 4M  [bh][seq][64]
    u16* kb      = qb + (size_t)4 * 1024 * 1024;     // 4M  [bh][seq][64]
    u16* vtb     = kb + (size_t)4 * 1024 * 1024;     // 4M  [bh][64][seq]
    // total 34 MB of ws

    cvt_bf16<<<2048, 256, 0, stream>>>(x, xbf, 4 * 1024 * 1024);
    cvt_bf16<<<1536, 256, 0, stream>>>(qkv_w, qkvwbf, 3 * 1024 * 1024);
    cvt_bf16<<<512, 256, 0, stream>>>(proj_w, projwbf, 1024 * 1024);

    // QKV projection + scatter (M=4096, N=3072)
    gemm_mfma<1><<<dim3(24, 32), 256, 0, stream>>>(xbf, qkvwbf, qkv_b, nullptr, qb, kb, vtb);
    // flash attention -> bf16 attn_out (reuses xbf region)
    attn_mfma<<<dim3(SEQ / 64, BATCH * NHEAD), 256, 0, stream>>>(qb, kb, vtb, xbf);
    // output projection (M=4096, N=1024) -> fp32 d_out
    gemm_mfma<0><<<dim3(8, 32), 256, 0, stream>>>(xbf, projwbf, proj_b, out, nullptr, nullptr, nullptr);
}

// Round 12
// 232.313 us; speedup vs baseline: 4.6004x; 1.1158x over previous
//
#include <hip/hip_runtime.h>
#include <hip/hip_bf16.h>
#include <math.h>

#define D_MODEL 1024
#define NHEAD 16
#define HDIM 64
#define BATCH 2
#define SEQ 2048
// q pre-scale folded into QKV epilogue: 1/sqrt(64) = 0.125 (EXACT power of 2:
// commutes with bf16 rounding, so Q bits match the unscaled-Q + post-scale path)
#define QSCALE 0.125f

typedef unsigned short u16;
typedef unsigned int u32;
typedef __attribute__((ext_vector_type(8))) short bf16x8;
typedef __attribute__((ext_vector_type(4))) short bf16x4;
typedef __attribute__((ext_vector_type(2))) u32 u32x2;
typedef __attribute__((ext_vector_type(4))) float f32x4;

__device__ __forceinline__ f32x4 mfma_bf16(bf16x8 a, bf16x8 b, f32x4 c) {
    return __builtin_amdgcn_mfma_f32_16x16x32_bf16(a, b, c, 0, 0, 0);
}
__device__ __forceinline__ f32x4 mfma16(bf16x4 a, bf16x4 b, f32x4 c) {
#if __has_builtin(__builtin_amdgcn_mfma_f32_16x16x16bf16_1k)
    return __builtin_amdgcn_mfma_f32_16x16x16bf16_1k(a, b, c, 0, 0, 0);
#else
    asm volatile("v_mfma_f32_16x16x16_bf16 %0, %1, %2, %0" : "+v"(c) : "v"(a), "v"(b));
    return c;
#endif
}
__device__ __forceinline__ void gload_lds16(const void* g, void* l) {
    __builtin_amdgcn_global_load_lds(
        (const __attribute__((address_space(1))) unsigned int*)g,
        (__attribute__((address_space(3))) unsigned int*)l, 16, 0, 0);
}
__device__ __forceinline__ u16 f2bf(float f) {
    unsigned u = __builtin_bit_cast(unsigned, f);
    return (u16)((u + 0x7FFFu + ((u >> 16) & 1u)) >> 16);
}
// RNE-packed pair of bf16 (avoids v_cvt_pk_bf16_f32: rounding mode unverified on gfx950)
__device__ __forceinline__ u32 pack_bf16(float lo, float hi) {
    return (u32)f2bf(lo) | ((u32)f2bf(hi) << 16);
}

// ---------------- f32 -> bf16 conversion (memory-bound) ----------------
__global__ __launch_bounds__(256) void cvt_bf16(const float* __restrict__ in,
                                                u16* __restrict__ out, int n) {
    int i = (blockIdx.x * 256 + threadIdx.x) * 8;
    if (i >= n) return;
    float4 a = *(const float4*)&in[i];
    float4 b = *(const float4*)&in[i + 4];
    ushort4 o0 = { f2bf(a.x), f2bf(a.y), f2bf(a.z), f2bf(a.w) };
    ushort4 o1 = { f2bf(b.x), f2bf(b.y), f2bf(b.z), f2bf(b.w) };
    *(ushort4*)&out[i] = o0;
    *(ushort4*)&out[i + 4] = o1;
}

// ---------------- MFMA GEMM: C[m][n] = sum_k A[m][k]*W[n][k] + bias ----------------
// 128x128 tile, BK=64, 4 waves each 64x64 (4x4 frags of 16x16x32).
// LDS tiles [128 rows][64 k] bf16 (128B rows), XOR swizzle byte^=((row&7)<<4):
// global_load_lds writes linearly; SOURCE address is inverse-swizzled (rule #21).
// MODE 0: fp32 out [M][1024] (+proj bias)
// MODE 1: bf16 scatter: n in [0,1024)=q (pre-scaled by QSCALE), [1024,2048)=k
//         -> [bh][seq][64]; [2048,3072)=v -> TRANSPOSED [bh][d][seq]
template<int MODE>
__global__ __launch_bounds__(256) void gemm_mfma(const u16* __restrict__ A,
                                                 const u16* __restrict__ W,
                                                 const float* __restrict__ bias,
                                                 float* __restrict__ outf,
                                                 u16* __restrict__ qw,
                                                 u16* __restrict__ kw,
                                                 u16* __restrict__ vtw)
{
    __shared__ u16 As[2][8192];
    __shared__ u16 Bs[2][8192];
    const int t = threadIdx.x, lane = t & 63, w = t >> 6;
    const int wr = w >> 1, wc = w & 1;
    const int lr = lane & 15, lk = lane >> 4;
    const int m0 = blockIdx.y * 128, n0 = blockIdx.x * 128;

    // staging constants: physical LDS byte p -> (row, inverse-swizzled k-offset)
    int srow[4], soff[4];
    #pragma unroll
    for (int i = 0; i < 4; ++i) {
        int p = (w * 4 + i) * 1024 + lane * 16;
        int row = p >> 7;
        srow[i] = row;
        soff[i] = ((p ^ ((row & 7) << 4)) & 127) >> 1;  // element offset in k
    }

    f32x4 acc[4][4];
    #pragma unroll
    for (int i = 0; i < 4; ++i)
        #pragma unroll
        for (int j = 0; j < 4; ++j)
            #pragma unroll
            for (int r = 0; r < 4; ++r) acc[i][j][r] = 0.f;

    auto stage = [&](int buf, int k0) {
        #pragma unroll
        for (int i = 0; i < 4; ++i) {
            gload_lds16(&A[(size_t)(m0 + srow[i]) * 1024 + k0 + soff[i]],
                        &As[buf][(w * 4 + i) * 512]);
            gload_lds16(&W[(size_t)(n0 + srow[i]) * 1024 + k0 + soff[i]],
                        &Bs[buf][(w * 4 + i) * 512]);
        }
    };

    stage(0, 0);
    __syncthreads();

    for (int kt = 0; kt < 16; ++kt) {
        int buf = kt & 1;
        if (kt < 15) stage(buf ^ 1, (kt + 1) * 64);
        #pragma unroll
        for (int kk = 0; kk < 2; ++kk) {
            const int kb2 = (kk * 32 + lk * 8) * 2;   // k byte offset within row
            bf16x8 am[4], bn[4];
            #pragma unroll
            for (int mf = 0; mf < 4; ++mf) {
                int row = wr * 64 + mf * 16 + lr;
                am[mf] = *(const bf16x8*)((const char*)As[buf] + row * 128 + (kb2 ^ ((row & 7) << 4)));
            }
            #pragma unroll
            for (int nf = 0; nf < 4; ++nf) {
                int row = wc * 64 + nf * 16 + lr;
                bn[nf] = *(const bf16x8*)((const char*)Bs[buf] + row * 128 + (kb2 ^ ((row & 7) << 4)));
            }
            #pragma unroll
            for (int mf = 0; mf < 4; ++mf)
                #pragma unroll
                for (int nf = 0; nf < 4; ++nf)
                    acc[mf][nf] = mfma_bf16(am[mf], bn[nf], acc[mf][nf]);
        }
        __syncthreads();
    }

    // epilogue: C/D layout col = lane&15, row = (lane>>4)*4 + reg
    if (MODE == 0) {
        #pragma unroll
        for (int nf = 0; nf < 4; ++nf) {
            int n = n0 + wc * 64 + nf * 16 + lr;
            float bv = bias[n];
            #pragma unroll
            for (int mf = 0; mf < 4; ++mf) {
                int m = m0 + wr * 64 + mf * 16 + lk * 4;
                #pragma unroll
                for (int r = 0; r < 4; ++r)
                    outf[(size_t)(m + r) * 1024 + n] = acc[mf][nf][r] + bv;
            }
        }
    } else {
        #pragma unroll
        for (int nf = 0; nf < 4; ++nf) {
            int n = n0 + wc * 64 + nf * 16 + lr;
            int which = n >> 10, h = (n >> 6) & 15, d = n & 63;
            float bv = bias[n];
            #pragma unroll
            for (int mf = 0; mf < 4; ++mf) {
                int m = m0 + wr * 64 + mf * 16 + lk * 4;
                int b = m >> 11, sq = m & 2047;
                int bh = b * NHEAD + h;
                if (which == 2) {
                    ushort4 v4;
                    v4.x = f2bf(acc[mf][nf][0] + bv);
                    v4.y = f2bf(acc[mf][nf][1] + bv);
                    v4.z = f2bf(acc[mf][nf][2] + bv);
                    v4.w = f2bf(acc[mf][nf][3] + bv);
                    *(ushort4*)&vtw[((size_t)bh * 64 + d) * SEQ + sq] = v4;
                } else if (which == 1) {
                    u16* dst = kw + ((size_t)bh * SEQ + sq) * 64 + d;
                    dst[0]   = f2bf(acc[mf][nf][0] + bv);
                    dst[64]  = f2bf(acc[mf][nf][1] + bv);
                    dst[128] = f2bf(acc[mf][nf][2] + bv);
                    dst[192] = f2bf(acc[mf][nf][3] + bv);
                } else {
                    u16* dst = qw + ((size_t)bh * SEQ + sq) * 64 + d;
                    dst[0]   = f2bf((acc[mf][nf][0] + bv) * QSCALE);
                    dst[64]  = f2bf((acc[mf][nf][1] + bv) * QSCALE);
                    dst[128] = f2bf((acc[mf][nf][2] + bv) * QSCALE);
                    dst[192] = f2bf((acc[mf][nf][3] + bv) * QSCALE);
                }
            }
        }
    }
}

// ---------------- Flash attention, bf16 MFMA, TRANSPOSED (lane-local softmax) ----
// block = 256 thr (4 waves), QBLK=64 (16 q-rows/wave), KVBLK=64.
// S^T = mfma(K, Q): lane holds S[q=lr][kv = nf*16 + lk*4 + r] -> row reductions are
// in-register trees + 2 shfl_xor. P packed to bf16 in-register (RNE) and fed as
// the B-operand of 16x16x16 MFMA (B k-layout (lane>>4)*4+r == C-layout kv spread:
// zero exchange). O^T = mfma(Vt, P). No P LDS buffer.
__global__ __launch_bounds__(256) void attn_mfma(const u16* __restrict__ qg,
                                                 const u16* __restrict__ kg,
                                                 const u16* __restrict__ vtg,
                                                 u16* __restrict__ og)
{
    __shared__ u16 Ks[2][4096];
    __shared__ u16 Vs[2][4096];
    const int t = threadIdx.x, lane = t & 63, w = t >> 6;
    const int lr = lane & 15, lk = lane >> 4;
    const int q0 = blockIdx.x * 64;
    const int bh = blockIdx.y;
    const u16* Qbh = qg + (size_t)bh * SEQ * 64;
    const char* Kbytes = (const char*)(kg + (size_t)bh * SEQ * 64);
    const char* Vbytes = (const char*)(vtg + (size_t)bh * 64 * SEQ);

    // Q B-frags direct to regs: B-col = q = lr -> q = q0 + w*16 + lr, k = kk*32 + lk*8
    bf16x8 qa[2];
    {
        const u16* qp = &Qbh[(size_t)(q0 + w * 16 + lr) * 64 + lk * 8];
        qa[0] = *(const bf16x8*)qp;
        qa[1] = *(const bf16x8*)(qp + 32);
    }

    int srow[2], soff[2];
    #pragma unroll
    for (int i = 0; i < 2; ++i) {
        int p = (w * 2 + i) * 1024 + lane * 16;
        int row = p >> 7;
        srow[i] = row;
        soff[i] = p ^ ((row & 7) << 4);   // inverse-swizzled byte offset (contains row*128)
    }

    auto stage = [&](int buf, int tt) {
        #pragma unroll
        for (int i = 0; i < 2; ++i) {
            gload_lds16(Kbytes + (size_t)tt * 8192 + soff[i], &Ks[buf][(w * 2 + i) * 512]);
            gload_lds16(Vbytes + (size_t)srow[i] * (SEQ * 2) + tt * 128 + (soff[i] & 127),
                        &Vs[buf][(w * 2 + i) * 512]);
        }
    };

    f32x4 o[4];   // O^T: lane holds O[q=lr][d = fd*16 + lk*4 + r]
    #pragma unroll
    for (int fd = 0; fd < 4; ++fd)
        #pragma unroll
        for (int r = 0; r < 4; ++r) o[fd][r] = 0.f;
    float mrow = -1e30f, lsum = 0.f;   // per-lane scalars (q = lr), ln domain

    stage(0, 0);
    __syncthreads();

    for (int kt = 0; kt < SEQ / 64; ++kt) {
        int buf = kt & 1;
        if (kt < SEQ / 64 - 1) stage(buf ^ 1, kt + 1);

        // S^T = K.Q^T : lane holds S[q=lr][kv = nf*16 + lk*4 + r] (pre-scaled by 1/8)
        f32x4 s[4];
        #pragma unroll
        for (int nf = 0; nf < 4; ++nf)
            #pragma unroll
            for (int r = 0; r < 4; ++r) s[nf][r] = 0.f;
        #pragma unroll
        for (int kk = 0; kk < 2; ++kk) {
            const int kb2 = (kk * 32 + lk * 8) * 2;
            #pragma unroll
            for (int nf = 0; nf < 4; ++nf) {
                int row = nf * 16 + lr;   // kv row
                bf16x8 kb = *(const bf16x8*)((const char*)Ks[buf] + row * 128 + (kb2 ^ ((row & 7) << 4)));
                s[nf] = mfma_bf16(kb, qa[kk], s[nf]);   // A=K (i=kv), B=Q (j=q)
            }
        }

        // online softmax, fully lane-local, ln domain (matches R7 numerics)
        float mx = s[0][0];
        #pragma unroll
        for (int nf = 0; nf < 4; ++nf)
            #pragma unroll
            for (int r = 0; r < 4; ++r) mx = fmaxf(mx, s[nf][r]);
        mx = fmaxf(mx, __shfl_xor(mx, 16));
        mx = fmaxf(mx, __shfl_xor(mx, 32));
        const float mN = fmaxf(mrow, mx);
        const float al = __expf(mrow - mN);
        float p[4][4];
        float rs = 0.f;
        #pragma unroll
        for (int nf = 0; nf < 4; ++nf) {
            float t0 = __expf(s[nf][0] - mN), t1 = __expf(s[nf][1] - mN);
            float t2 = __expf(s[nf][2] - mN), t3 = __expf(s[nf][3] - mN);
            p[nf][0] = t0; p[nf][1] = t1; p[nf][2] = t2; p[nf][3] = t3;
            rs += (t0 + t1) + (t2 + t3);
        }
        rs += __shfl_xor(rs, 16);
        rs += __shfl_xor(rs, 32);
        lsum = lsum * al + rs;
        mrow = mN;
        #pragma unroll
        for (int fd = 0; fd < 4; ++fd)
            #pragma unroll
            for (int r = 0; r < 4; ++r) o[fd][r] *= al;

        // O^T += Vt.P : 16x16x16 MFMA, A = Vt (i=d, k=kv), B = P in-register (j=q, k=kv)
        #pragma unroll
        for (int nf = 0; nf < 4; ++nf) {
            u32x2 pw;
            pw[0] = pack_bf16(p[nf][0], p[nf][1]);
            pw[1] = pack_bf16(p[nf][2], p[nf][3]);
            bf16x4 pb = __builtin_bit_cast(bf16x4, pw);
            const int kvb = nf * 32 + lk * 8;   // byte offset of kv = nf*16 + lk*4
            #pragma unroll
            for (int fd = 0; fd < 4; ++fd) {
                int row = fd * 16 + lr;   // d row in Vt tile
                bf16x4 vb = *(const bf16x4*)((const char*)Vs[buf] + row * 128 + (kvb ^ ((row & 7) << 4)));
                o[fd] = mfma16(vb, pb, o[fd]);
            }
        }
        __syncthreads();
    }

    // epilogue: lane owns q = q0 + w*16 + lr; d = fd*16 + lk*4 + r (ushort4 stores)
    const int b = bh >> 4, h = bh & 15;
    const float inv = 1.0f / lsum;
    const size_t orow = (size_t)(b * SEQ + q0 + w * 16 + lr) * D_MODEL;
    #pragma unroll
    for (int fd = 0; fd < 4; ++fd) {
        ushort4 st;
        st.x = f2bf(o[fd][0] * inv);
        st.y = f2bf(o[fd][1] * inv);
        st.z = f2bf(o[fd][2] * inv);
        st.w = f2bf(o[fd][3] * inv);
        *(ushort4*)&og[orow + h * 64 + fd * 16 + lk * 4] = st;
    }
}

extern "C" void kernel_launch(void* const* d_in, const int* in_sizes, int n_in,
                              void* d_out, int out_size, void* d_ws, size_t ws_size,
                              hipStream_t stream)
{
    const float* x      = (const float*)d_in[0];
    const float* qkv_w  = (const float*)d_in[1];
    const float* qkv_b  = (const float*)d_in[2];
    const float* proj_w = (const float*)d_in[3];
    const float* proj_b = (const float*)d_in[4];
    float* out = (float*)d_out;

    u16* xbf     = (u16*)d_ws;                       // 4M elems; later reused as attn_out bf16
    u16* qkvwbf  = xbf + (size_t)4 * 1024 * 1024;    // 3M
    u16* projwbf = qkvwbf + (size_t)3 * 1024 * 1024; // 1M
    u16* qb      = projwbf + (size_t)1024 * 1024;    // 4M  [bh][seq][64] (pre-scaled)
    u16* kb      = qb + (size_t)4 * 1024 * 1024;     // 4M  [bh][seq][64]
    u16* vtb     = kb + (size_t)4 * 1024 * 1024;     // 4M  [bh][64][seq]
    // total 34 MB of ws

    cvt_bf16<<<2048, 256, 0, stream>>>(x, xbf, 4 * 1024 * 1024);
    cvt_bf16<<<1536, 256, 0, stream>>>(qkv_w, qkvwbf, 3 * 1024 * 1024);
    cvt_bf16<<<512, 256, 0, stream>>>(proj_w, projwbf, 1024 * 1024);

    // QKV projection + scatter (M=4096, N=3072)
    gemm_mfma<1><<<dim3(24, 32), 256, 0, stream>>>(xbf, qkvwbf, qkv_b, nullptr, qb, kb, vtb);
    // flash attention -> bf16 attn_out (reuses xbf region)
    attn_mfma<<<dim3(SEQ / 64, BATCH * NHEAD), 256, 0, stream>>>(qb, kb, vtb, xbf);
    // output projection (M=4096, N=1024) -> fp32 d_out
    gemm_mfma<0><<<dim3(8, 32), 256, 0, stream>>>(xbf, projwbf, proj_b, out, nullptr, nullptr, nullptr);
}